// Round 1
// 853.187 us; speedup vs baseline: 1.1245x; 1.1245x over previous
//
#include <hip/hip_runtime.h>
#include <hip/hip_bf16.h>
#include <stdint.h>

// ---- problem constants -----------------------------------------------------
#define B_    8
#define T_    256
#define U_    64
#define JD    512              // joint dim (N of projections, K of gemm3)
#define VD    1024             // vocab
#define ROWS  (B_*T_*U_)       // 131072 joint rows
#define MTOT  (B_*T_)          // 2048 enc rows
#define UROWS (B_*U_)          // 512 pred rows

typedef __attribute__((ext_vector_type(8))) short short8;   // 8 bf16 = 4 VGPR
typedef __attribute__((ext_vector_type(4))) float f32x4;

// ---- helpers ---------------------------------------------------------------
__device__ __forceinline__ unsigned short f2bf(float f) {   // RNE
  unsigned u = __float_as_uint(f);
  u += 0x7fffu + ((u >> 16) & 1u);
  return (unsigned short)(u >> 16);
}
// tanh(x) = 1 - 2/(exp2(2*log2e*x)+1); handles +-inf gracefully (-> +-1)
__device__ __forceinline__ float fast_tanh(float x) {
  float e = __builtin_amdgcn_exp2f(x * 2.8853900817779268f);
  return 1.0f - 2.0f * __builtin_amdgcn_rcpf(e + 1.0f);
}

// ---- W pack body: row-major fp32 [K][N] -> bf16 B-fragment layout ----------
// frag(nt16, kc): lane l holds B[k=kc*32+(l>>4)*8+j][n=nt16*16+(l&15)], j=0..7
// dst short index: (((nt16*(K/32)+kc)*64 + lane)*8 + j)
__device__ __forceinline__ void pack_w_body(const float* __restrict__ W,
                                            unsigned short* __restrict__ dst,
                                            int K, int N, int t) {
  int lane = t & 63;
  int rest = t >> 6;
  int kch  = K >> 5;
  int kc   = rest % kch;
  int nt   = rest / kch;
  int krow = (kc << 5) + ((lane >> 4) << 3);
  int col  = (nt << 4) + (lane & 15);
  unsigned short v[8];
#pragma unroll
  for (int j = 0; j < 8; ++j) v[j] = f2bf(W[(size_t)(krow + j) * N + col]);
  uint4 o;
  o.x = v[0] | ((unsigned)v[1] << 16);
  o.y = v[2] | ((unsigned)v[3] << 16);
  o.z = v[4] | ((unsigned)v[5] << 16);
  o.w = v[6] | ((unsigned)v[7] << 16);
  *(uint4*)(dst + ((size_t)t << 3)) = o;
}

// all three weight packs in one launch (grids exact: 128 + 160 + 256 blocks)
__global__ void __launch_bounds__(256) k_pack_all(
    const float* __restrict__ We, const float* __restrict__ Wp,
    const float* __restrict__ Wj,
    unsigned short* __restrict__ de, unsigned short* __restrict__ dp,
    unsigned short* __restrict__ dj) {
  int blk = blockIdx.x;
  int tid = threadIdx.x;
  if (blk < 128)      pack_w_body(We, de, 512, 512,  blk * 256 + tid);
  else if (blk < 288) pack_w_body(Wp, dp, 640, 512,  (blk - 128) * 256 + tid);
  else                pack_w_body(Wj, dj, 512, 1024, (blk - 288) * 256 + tid);
}

// ---- projection GEMM body: C[M][N] fp32 = A_fp32[M][K] @ Bpacked + bias ----
// wave-tile 16 rows x 64 cols, no LDS
__device__ __forceinline__ void proj_body(const float* __restrict__ A,
    const unsigned short* __restrict__ Bp, const float* __restrict__ bias,
    float* __restrict__ C, int M, int K, int N, int w, int lane) {
  int nw = N >> 6;                      // waves along N
  int wm = w / nw, wn = w % nw;
  int m0 = wm << 4, n0 = wn << 6;
  if (m0 >= M) return;
  int kch = K >> 5;
  int q = lane >> 4, c = lane & 15;
  f32x4 acc[4] = {f32x4{0,0,0,0}, f32x4{0,0,0,0}, f32x4{0,0,0,0}, f32x4{0,0,0,0}};
  const float* arow = A + (size_t)(m0 + c) * K + (q << 3);
  for (int kc = 0; kc < kch; ++kc) {
    float4 a0 = *(const float4*)(arow + (kc << 5));
    float4 a1 = *(const float4*)(arow + (kc << 5) + 4);
    short8 a;
    a[0] = (short)f2bf(a0.x); a[1] = (short)f2bf(a0.y);
    a[2] = (short)f2bf(a0.z); a[3] = (short)f2bf(a0.w);
    a[4] = (short)f2bf(a1.x); a[5] = (short)f2bf(a1.y);
    a[6] = (short)f2bf(a1.z); a[7] = (short)f2bf(a1.w);
#pragma unroll
    for (int j = 0; j < 4; ++j) {
      size_t nt16 = (size_t)((n0 >> 4) + j);
      short8 b = *(const short8*)(Bp + (((nt16 * kch + kc) << 6) + lane) * 8);
      acc[j] = __builtin_amdgcn_mfma_f32_16x16x32_bf16(a, b, acc[j], 0, 0, 0);
    }
  }
#pragma unroll
  for (int j = 0; j < 4; ++j) {
    int col = n0 + (j << 4) + c;
    float bv = bias[col];
#pragma unroll
    for (int r = 0; r < 4; ++r) {
      int row = m0 + (q << 2) + r;          // C/D: row=(lane>>4)*4+reg
      C[(size_t)row * N + col] = acc[j][r] + bv;
    }
  }
}

// both projections in one launch: blocks 0..255 enc (1024 waves), 256..319 pred
__global__ void __launch_bounds__(256) k_proj_both(
    const float* __restrict__ enc_out, const float* __restrict__ pred_out,
    const unsigned short* __restrict__ Wep, const unsigned short* __restrict__ Wpp,
    const float* __restrict__ b_enc, const float* __restrict__ b_pred,
    float* __restrict__ enc_p, float* __restrict__ pred_p) {
  int blk  = blockIdx.x;
  int lane = threadIdx.x & 63;
  int wloc = threadIdx.x >> 6;
  if (blk < 256)
    proj_body(enc_out,  Wep, b_enc,  enc_p,  MTOT,  512, JD, blk * 4 + wloc, lane);
  else
    proj_body(pred_out, Wpp, b_pred, pred_p, UROWS, 640, JD, (blk - 256) * 4 + wloc, lane);
}

// ---- fused tanh + main GEMM ------------------------------------------------
// out[ROWS][VD] = tanh(enc_p[bt] + pred_p[bu]) @ Wjnt + b_joint
// block: 512 thr (8 waves, 2x4), tile 128 rows x 256 cols; K chunked by 128.
// Per chunk: all threads tanh-pack A(128x128) into LDS bf16 fragments
// (contiguous 1KiB per frag -> conflict-free b128 LDS ops), barrier, MFMA with
// B frags direct from global (1 MiB total, L2-hot). tanh redundancy = VD/256 = 4.
__global__ void __launch_bounds__(512, 4) k_fused(
    const float* __restrict__ enc_p, const float* __restrict__ pred_p,
    const unsigned short* __restrict__ Bp, const float* __restrict__ bias,
    float* __restrict__ out) {
  __shared__ unsigned short Alds[32 * 64 * 8];       // 32 frags x 1 KiB = 32 KiB
  const short8* a8 = (const short8*)Alds;
  const short8* b8 = (const short8*)Bp;

  int bid  = blockIdx.x;
  int nt   = bid & 3;               // N-block (256 cols); n fastest -> A stripe shared
  int mt   = bid >> 2;              // M-block (128 rows)
  int tid  = threadIdx.x;
  int lane = tid & 63;
  int w    = tid >> 6;              // 0..7
  int wm   = w >> 2, wn = w & 3;    // 2 x 4 wave grid, wave tile 64x64
  int rb0w = wm << 2;               // wave's first local 16-row unit (0 or 4)
  int nt0w = (nt << 4) + (wn << 2); // wave's first global 16-col unit
  int c15  = lane & 15, q8 = (lane >> 4) << 3;

  f32x4 acc[4][4];
#pragma unroll
  for (int i = 0; i < 4; ++i)
#pragma unroll
    for (int j = 0; j < 4; ++j) acc[i][j] = f32x4{0, 0, 0, 0};

  for (int ch = 0; ch < 4; ++ch) {
    int kbase = ch << 7;
    // ---- phase 1: tanh-pack A chunk (128 rows x 128 k) into LDS frags ----
    // frag(rb,kcl): lane l holds A[m=rb*16+(l&15)][k=kbase+kcl*32+(l>>4)*8+j]
#pragma unroll 2
    for (int ff = 0; ff < 4; ++ff) {
      int f   = w + (ff << 3);          // 0..31
      int rb  = f >> 2, kcl = f & 3;
      int r   = (mt << 7) + (rb << 4) + c15;               // global joint row
      int k0  = kbase + (kcl << 5) + q8;
      const float* ep = enc_p  + ((size_t)(r >> 6) << 9) + k0;  // bt = r>>6 (broadcast)
      const float* pp = pred_p + ((size_t)(((r >> 14) << 6) + (r & 63)) << 9) + k0;
      float4 e0 = *(const float4*)ep, e1 = *(const float4*)(ep + 4);
      float4 p0 = *(const float4*)pp, p1 = *(const float4*)(pp + 4);
      unsigned short v[8];
      v[0] = f2bf(fast_tanh(e0.x + p0.x));
      v[1] = f2bf(fast_tanh(e0.y + p0.y));
      v[2] = f2bf(fast_tanh(e0.z + p0.z));
      v[3] = f2bf(fast_tanh(e0.w + p0.w));
      v[4] = f2bf(fast_tanh(e1.x + p1.x));
      v[5] = f2bf(fast_tanh(e1.y + p1.y));
      v[6] = f2bf(fast_tanh(e1.z + p1.z));
      v[7] = f2bf(fast_tanh(e1.w + p1.w));
      uint4 o;
      o.x = v[0] | ((unsigned)v[1] << 16);
      o.y = v[2] | ((unsigned)v[3] << 16);
      o.z = v[4] | ((unsigned)v[5] << 16);
      o.w = v[6] | ((unsigned)v[7] << 16);
      *(uint4*)(Alds + ((((rb << 2) + kcl) << 6) + lane) * 8) = o;
    }
    __syncthreads();
    // ---- phase 2: MFMA over this K chunk ----
#pragma unroll
    for (int kcl = 0; kcl < 4; ++kcl) {
      int kc = (ch << 2) + kcl;
      short8 a[4], b[4];
#pragma unroll
      for (int i = 0; i < 4; ++i)
        a[i] = a8[(((rb0w + i) << 2) + kcl) * 64 + lane];
#pragma unroll
      for (int j = 0; j < 4; ++j)
        b[j] = b8[(((size_t)(nt0w + j) << 4) + kc) * 64 + lane];
#pragma unroll
      for (int i = 0; i < 4; ++i)
#pragma unroll
        for (int j = 0; j < 4; ++j)
          acc[i][j] = __builtin_amdgcn_mfma_f32_16x16x32_bf16(a[i], b[j], acc[i][j], 0, 0, 0);
    }
    __syncthreads();
  }

  // ---- epilogue: bias + store (C/D: col=lane&15, row=(lane>>4)*4+reg) ----
  int q = lane >> 4;
#pragma unroll
  for (int j = 0; j < 4; ++j) {
    int col = ((nt0w + j) << 4) + c15;
    float bv = bias[col];
#pragma unroll
    for (int i = 0; i < 4; ++i) {
      int row = (mt << 7) + ((rb0w + i) << 4) + (q << 2);
      size_t o = ((size_t)row << 10) + col;
#pragma unroll
      for (int rr = 0; rr < 4; ++rr)
        out[o + ((size_t)rr << 10)] = acc[i][j][rr] + bv;
    }
  }
}

// ---- fallbacks (only if ws_size is too small) ------------------------------
__global__ void __launch_bounds__(256) k_proj_naive(
    const float* __restrict__ A, const float* __restrict__ W,
    const float* __restrict__ bias, float* __restrict__ C,
    int M, int K, int N) {
  int t = blockIdx.x * blockDim.x + threadIdx.x;
  if (t >= M * N) return;
  int row = t / N, col = t % N;
  float s = bias[col];
  for (int k = 0; k < K; ++k)
    s += A[(size_t)row * K + k] * W[(size_t)k * N + col];
  C[t] = s;
}
__global__ void __launch_bounds__(256) k_joint_naive(
    const float* __restrict__ enc_p, const float* __restrict__ pred_p,
    const float* __restrict__ Wj, const float* __restrict__ bj,
    float* __restrict__ out) {
  __shared__ float jrow[JD];
  int gr = blockIdx.x;
  int bt = gr >> 6;
  int bu = ((gr >> 14) << 6) + (gr & 63);
  for (int k = threadIdx.x; k < JD; k += 256)
    jrow[k] = fast_tanh(enc_p[(size_t)bt * JD + k] + pred_p[(size_t)bu * JD + k]);
  __syncthreads();
  int v0 = threadIdx.x * 4;
  float s0 = bj[v0], s1 = bj[v0 + 1], s2 = bj[v0 + 2], s3 = bj[v0 + 3];
  for (int k = 0; k < JD; ++k) {
    float jv = jrow[k];
    const float* wr = Wj + (size_t)k * VD + v0;
    s0 += jv * wr[0];
    s1 += jv * wr[1];
    s2 += jv * wr[2];
    s3 += jv * wr[3];
  }
  size_t o = ((size_t)gr << 10) + v0;
  out[o] = s0; out[o + 1] = s1; out[o + 2] = s2; out[o + 3] = s3;
}

// ---- host ------------------------------------------------------------------
extern "C" void kernel_launch(void* const* d_in, const int* in_sizes, int n_in,
                              void* d_out, int out_size, void* d_ws, size_t ws_size,
                              hipStream_t stream) {
  const float* enc_out  = (const float*)d_in[0];
  const float* pred_out = (const float*)d_in[1];
  const float* W_enc    = (const float*)d_in[2];
  const float* b_enc    = (const float*)d_in[3];
  const float* W_pred   = (const float*)d_in[4];
  const float* b_pred   = (const float*)d_in[5];
  const float* W_joint  = (const float*)d_in[6];
  const float* b_joint  = (const float*)d_in[7];
  float* out = (float*)d_out;

  char* ws = (char*)d_ws;
  size_t off = 0;
  auto alloc = [&](size_t bytes) -> char* {
    char* p = ws + off;
    off += (bytes + 255) & ~(size_t)255;
    return p;
  };
  float* enc_p  = (float*)alloc((size_t)MTOT * JD * 4);    // 4 MB
  float* pred_p = (float*)alloc((size_t)UROWS * JD * 4);   // 1 MB
  size_t small_need = off;
  unsigned short* Wenc_p  = (unsigned short*)alloc((size_t)512 * 512 * 2);
  unsigned short* Wpred_p = (unsigned short*)alloc((size_t)640 * 512 * 2);
  unsigned short* Wjnt_p  = (unsigned short*)alloc((size_t)512 * 1024 * 2);
  size_t big_need = off;                                   // ~7.3 MB total

  if (ws_size >= big_need) {
    k_pack_all<<<544, 256, 0, stream>>>(W_enc, W_pred, W_joint,
                                        Wenc_p, Wpred_p, Wjnt_p);
    k_proj_both<<<320, 256, 0, stream>>>(enc_out, pred_out, Wenc_p, Wpred_p,
                                         b_enc, b_pred, enc_p, pred_p);
    k_fused<<<(ROWS / 128) * (VD / 256), 512, 0, stream>>>(enc_p, pred_p,
                                                           Wjnt_p, b_joint, out);
  } else if (ws_size >= small_need) {
    k_proj_naive<<<(MTOT * JD + 255) / 256, 256, 0, stream>>>(enc_out, W_enc, b_enc, enc_p, MTOT, 512, JD);
    k_proj_naive<<<(UROWS * JD + 255) / 256, 256, 0, stream>>>(pred_out, W_pred, b_pred, pred_p, UROWS, 640, JD);
    k_joint_naive<<<ROWS, 256, 0, stream>>>(enc_p, pred_p, W_joint, b_joint, out);
  }
  (void)in_sizes; (void)n_in; (void)out_size;
}

// Round 2
// 793.289 us; speedup vs baseline: 1.2094x; 1.0755x over previous
//
#include <hip/hip_runtime.h>
#include <hip/hip_bf16.h>
#include <stdint.h>

// ---- problem constants -----------------------------------------------------
#define B_    8
#define T_    256
#define U_    64
#define JD    512              // joint dim (N of projections, K of gemm3)
#define VD    1024             // vocab
#define ROWS  (B_*T_*U_)       // 131072 joint rows
#define MTOT  (B_*T_)          // 2048 enc rows
#define UROWS (B_*U_)          // 512 pred rows

typedef __attribute__((ext_vector_type(8))) short short8;   // 8 bf16 = 4 VGPR
typedef __attribute__((ext_vector_type(4))) float f32x4;

// ---- helpers ---------------------------------------------------------------
__device__ __forceinline__ unsigned short f2bf(float f) {   // RNE
  unsigned u = __float_as_uint(f);
  u += 0x7fffu + ((u >> 16) & 1u);
  return (unsigned short)(u >> 16);
}
// tanh(x) = 1 - 2/(exp2(2*log2e*x)+1); handles +-inf gracefully (-> +-1)
__device__ __forceinline__ float fast_tanh(float x) {
  float e = __builtin_amdgcn_exp2f(x * 2.8853900817779268f);
  return 1.0f - 2.0f * __builtin_amdgcn_rcpf(e + 1.0f);
}
__device__ __forceinline__ uint4 tanh_pack8(float4 e0, float4 e1,
                                            float4 p0, float4 p1) {
  unsigned short v[8];
  v[0] = f2bf(fast_tanh(e0.x + p0.x));
  v[1] = f2bf(fast_tanh(e0.y + p0.y));
  v[2] = f2bf(fast_tanh(e0.z + p0.z));
  v[3] = f2bf(fast_tanh(e0.w + p0.w));
  v[4] = f2bf(fast_tanh(e1.x + p1.x));
  v[5] = f2bf(fast_tanh(e1.y + p1.y));
  v[6] = f2bf(fast_tanh(e1.z + p1.z));
  v[7] = f2bf(fast_tanh(e1.w + p1.w));
  uint4 o;
  o.x = v[0] | ((unsigned)v[1] << 16);
  o.y = v[2] | ((unsigned)v[3] << 16);
  o.z = v[4] | ((unsigned)v[5] << 16);
  o.w = v[6] | ((unsigned)v[7] << 16);
  return o;
}

// ---- W pack body: row-major fp32 [K][N] -> bf16 B-fragment layout ----------
// frag(nt16, kc): lane l holds B[k=kc*32+(l>>4)*8+j][n=nt16*16+(l&15)], j=0..7
// dst short index: (((nt16*(K/32)+kc)*64 + lane)*8 + j)
__device__ __forceinline__ void pack_w_body(const float* __restrict__ W,
                                            unsigned short* __restrict__ dst,
                                            int K, int N, int t) {
  int lane = t & 63;
  int rest = t >> 6;
  int kch  = K >> 5;
  int kc   = rest % kch;
  int nt   = rest / kch;
  int krow = (kc << 5) + ((lane >> 4) << 3);
  int col  = (nt << 4) + (lane & 15);
  unsigned short v[8];
#pragma unroll
  for (int j = 0; j < 8; ++j) v[j] = f2bf(W[(size_t)(krow + j) * N + col]);
  uint4 o;
  o.x = v[0] | ((unsigned)v[1] << 16);
  o.y = v[2] | ((unsigned)v[3] << 16);
  o.z = v[4] | ((unsigned)v[5] << 16);
  o.w = v[6] | ((unsigned)v[7] << 16);
  *(uint4*)(dst + ((size_t)t << 3)) = o;
}

// all three weight packs in one launch (grids exact: 128 + 160 + 256 blocks)
__global__ void __launch_bounds__(256) k_pack_all(
    const float* __restrict__ We, const float* __restrict__ Wp,
    const float* __restrict__ Wj,
    unsigned short* __restrict__ de, unsigned short* __restrict__ dp,
    unsigned short* __restrict__ dj) {
  int blk = blockIdx.x;
  int tid = threadIdx.x;
  if (blk < 128)      pack_w_body(We, de, 512, 512,  blk * 256 + tid);
  else if (blk < 288) pack_w_body(Wp, dp, 640, 512,  (blk - 128) * 256 + tid);
  else                pack_w_body(Wj, dj, 512, 1024, (blk - 288) * 256 + tid);
}

// ---- projection GEMM body: C[M][N] fp32 = A_fp32[M][K] @ Bpacked + bias ----
// wave-tile 16 rows x 64 cols, no LDS
__device__ __forceinline__ void proj_body(const float* __restrict__ A,
    const unsigned short* __restrict__ Bp, const float* __restrict__ bias,
    float* __restrict__ C, int M, int K, int N, int w, int lane) {
  int nw = N >> 6;                      // waves along N
  int wm = w / nw, wn = w % nw;
  int m0 = wm << 4, n0 = wn << 6;
  if (m0 >= M) return;
  int kch = K >> 5;
  int q = lane >> 4, c = lane & 15;
  f32x4 acc[4] = {f32x4{0,0,0,0}, f32x4{0,0,0,0}, f32x4{0,0,0,0}, f32x4{0,0,0,0}};
  const float* arow = A + (size_t)(m0 + c) * K + (q << 3);
  for (int kc = 0; kc < kch; ++kc) {
    float4 a0 = *(const float4*)(arow + (kc << 5));
    float4 a1 = *(const float4*)(arow + (kc << 5) + 4);
    short8 a;
    a[0] = (short)f2bf(a0.x); a[1] = (short)f2bf(a0.y);
    a[2] = (short)f2bf(a0.z); a[3] = (short)f2bf(a0.w);
    a[4] = (short)f2bf(a1.x); a[5] = (short)f2bf(a1.y);
    a[6] = (short)f2bf(a1.z); a[7] = (short)f2bf(a1.w);
#pragma unroll
    for (int j = 0; j < 4; ++j) {
      size_t nt16 = (size_t)((n0 >> 4) + j);
      short8 b = *(const short8*)(Bp + (((nt16 * kch + kc) << 6) + lane) * 8);
      acc[j] = __builtin_amdgcn_mfma_f32_16x16x32_bf16(a, b, acc[j], 0, 0, 0);
    }
  }
#pragma unroll
  for (int j = 0; j < 4; ++j) {
    int col = n0 + (j << 4) + c;
    float bv = bias[col];
#pragma unroll
    for (int r = 0; r < 4; ++r) {
      int row = m0 + (q << 2) + r;          // C/D: row=(lane>>4)*4+reg
      C[(size_t)row * N + col] = acc[j][r] + bv;
    }
  }
}

// both projections in one launch: blocks 0..255 enc (1024 waves), 256..319 pred
__global__ void __launch_bounds__(256) k_proj_both(
    const float* __restrict__ enc_out, const float* __restrict__ pred_out,
    const unsigned short* __restrict__ Wep, const unsigned short* __restrict__ Wpp,
    const float* __restrict__ b_enc, const float* __restrict__ b_pred,
    float* __restrict__ enc_p, float* __restrict__ pred_p) {
  int blk  = blockIdx.x;
  int lane = threadIdx.x & 63;
  int wloc = threadIdx.x >> 6;
  if (blk < 256)
    proj_body(enc_out,  Wep, b_enc,  enc_p,  MTOT,  512, JD, blk * 4 + wloc, lane);
  else
    proj_body(pred_out, Wpp, b_pred, pred_p, UROWS, 640, JD, (blk - 256) * 4 + wloc, lane);
}

// ---- fused tanh + main GEMM ------------------------------------------------
// out[ROWS][VD] = tanh(enc_p[bt] + pred_p[bu]) @ Wjnt + b_joint
// Block: 512 thr (8 waves, 2x4), tile 128 rows x 256 cols.
// K pipelined in 16 chunks of 32, LDS double-buffered (2 x 8 KiB):
//   issue e/p loads for chunk k+1 -> MFMA on chunk k -> tanh+write buf^1 -> barrier
// XCD-swizzled bid: each XCD owns a contiguous 128-mt stripe so its L2 holds
// its enc_p slice (512KB) + pred_p (128KB) + Bp (1MB). Output stores are
// non-temporal so the 537MB stream doesn't evict them.
__global__ void __launch_bounds__(512, 4) k_fused(
    const float* __restrict__ enc_p, const float* __restrict__ pred_p,
    const unsigned short* __restrict__ Bp, const float* __restrict__ bias,
    float* __restrict__ out) {
  __shared__ unsigned short Alds[2 * 8 * 64 * 8];    // 2 buffers x 8 KiB

  int bid  = blockIdx.x;
  int swz  = ((bid & 7) << 9) + (bid >> 3);   // bijective, 4096 % 8 == 0
  int nt   = swz & 3;                          // N-block (256 cols)
  int mt   = swz >> 2;                         // M-block (128 rows)
  int tid  = threadIdx.x;
  int lane = tid & 63;
  int w    = tid >> 6;               // 0..7
  int wm   = w >> 2, wn = w & 3;     // 2 x 4 wave grid, wave tile 64x64
  int rb0w = wm << 2;                // wave's first local 16-row unit (0 or 4)
  int nt0w = (nt << 4) + (wn << 2);  // wave's first global 16-col unit
  int c15  = lane & 15, q8 = (lane >> 4) << 3;

  // tanh-pack source: thread (w,lane) owns frag rb=w:
  //   A[m = mt*128 + w*16 + c15][k = kc*32 + q8 + j]
  int r = (mt << 7) + (w << 4) + c15;
  const float* ep = enc_p  + ((size_t)(r >> 6) << 9) + q8;
  const float* pp = pred_p + ((size_t)(((r >> 14) << 6) + (r & 63)) << 9) + q8;
  unsigned short* myA = Alds + (((w << 6) + lane) << 3);  // + buf*4096 shorts

  const short8* b8 = (const short8*)Bp;

  f32x4 acc[4][4];
#pragma unroll
  for (int i = 0; i < 4; ++i)
#pragma unroll
    for (int j = 0; j < 4; ++j) acc[i][j] = f32x4{0, 0, 0, 0};

  // prologue: chunk 0 -> buf 0
  {
    float4 e0 = *(const float4*)ep,       e1 = *(const float4*)(ep + 4);
    float4 p0 = *(const float4*)pp,       p1 = *(const float4*)(pp + 4);
    *(uint4*)myA = tanh_pack8(e0, e1, p0, p1);
  }
  __syncthreads();

  for (int kc = 0; kc < 16; ++kc) {
    int cur = kc & 1;
    // issue next chunk's e/p loads first (longest latency to cover)
    float4 ne0, ne1, np0, np1;
    if (kc < 15) {
      const float* e = ep + ((kc + 1) << 5);
      const float* p = pp + ((kc + 1) << 5);
      ne0 = *(const float4*)e; ne1 = *(const float4*)(e + 4);
      np0 = *(const float4*)p; np1 = *(const float4*)(p + 4);
    }
    // B frags for this chunk (L2-hot)
    short8 b[4];
#pragma unroll
    for (int j = 0; j < 4; ++j)
      b[j] = b8[(((size_t)(nt0w + j) << 4) + kc) * 64 + lane];
    // A frags from LDS
    const short8* abuf = (const short8*)(Alds + (cur << 12));
    short8 a[4];
#pragma unroll
    for (int i = 0; i < 4; ++i)
      a[i] = abuf[((rb0w + i) << 6) + lane];
    // MFMA cluster
    __builtin_amdgcn_s_setprio(1);
#pragma unroll
    for (int i = 0; i < 4; ++i)
#pragma unroll
      for (int j = 0; j < 4; ++j)
        acc[i][j] = __builtin_amdgcn_mfma_f32_16x16x32_bf16(a[i], b[j], acc[i][j], 0, 0, 0);
    __builtin_amdgcn_s_setprio(0);
    // tanh + write next chunk into the other buffer
    if (kc < 15)
      *(uint4*)(myA + ((cur ^ 1) << 12)) = tanh_pack8(ne0, ne1, np0, np1);
    __syncthreads();
  }

  // ---- epilogue: bias + non-temporal stores, full 128B lines per row ----
  float bv[4];
#pragma unroll
  for (int j = 0; j < 4; ++j) bv[j] = bias[((nt0w + j) << 4) + c15];
  int q = lane >> 4;
#pragma unroll
  for (int i = 0; i < 4; ++i) {
#pragma unroll
    for (int rr = 0; rr < 4; ++rr) {
      int row = (mt << 7) + ((rb0w + i) << 4) + (q << 2) + rr;
      size_t o = ((size_t)row << 10);
#pragma unroll
      for (int j = 0; j < 4; ++j) {
        int col = ((nt0w + j) << 4) + c15;
        __builtin_nontemporal_store(acc[i][j][rr] + bv[j], &out[o + col]);
      }
    }
  }
}

// ---- fallbacks (only if ws_size is too small) ------------------------------
__global__ void __launch_bounds__(256) k_proj_naive(
    const float* __restrict__ A, const float* __restrict__ W,
    const float* __restrict__ bias, float* __restrict__ C,
    int M, int K, int N) {
  int t = blockIdx.x * blockDim.x + threadIdx.x;
  if (t >= M * N) return;
  int row = t / N, col = t % N;
  float s = bias[col];
  for (int k = 0; k < K; ++k)
    s += A[(size_t)row * K + k] * W[(size_t)k * N + col];
  C[t] = s;
}
__global__ void __launch_bounds__(256) k_joint_naive(
    const float* __restrict__ enc_p, const float* __restrict__ pred_p,
    const float* __restrict__ Wj, const float* __restrict__ bj,
    float* __restrict__ out) {
  __shared__ float jrow[JD];
  int gr = blockIdx.x;
  int bt = gr >> 6;
  int bu = ((gr >> 14) << 6) + (gr & 63);
  for (int k = threadIdx.x; k < JD; k += 256)
    jrow[k] = fast_tanh(enc_p[(size_t)bt * JD + k] + pred_p[(size_t)bu * JD + k]);
  __syncthreads();
  int v0 = threadIdx.x * 4;
  float s0 = bj[v0], s1 = bj[v0 + 1], s2 = bj[v0 + 2], s3 = bj[v0 + 3];
  for (int k = 0; k < JD; ++k) {
    float jv = jrow[k];
    const float* wr = Wj + (size_t)k * VD + v0;
    s0 += jv * wr[0];
    s1 += jv * wr[1];
    s2 += jv * wr[2];
    s3 += jv * wr[3];
  }
  size_t o = ((size_t)gr << 10) + v0;
  out[o] = s0; out[o + 1] = s1; out[o + 2] = s2; out[o + 3] = s3;
}

// ---- host ------------------------------------------------------------------
extern "C" void kernel_launch(void* const* d_in, const int* in_sizes, int n_in,
                              void* d_out, int out_size, void* d_ws, size_t ws_size,
                              hipStream_t stream) {
  const float* enc_out  = (const float*)d_in[0];
  const float* pred_out = (const float*)d_in[1];
  const float* W_enc    = (const float*)d_in[2];
  const float* b_enc    = (const float*)d_in[3];
  const float* W_pred   = (const float*)d_in[4];
  const float* b_pred   = (const float*)d_in[5];
  const float* W_joint  = (const float*)d_in[6];
  const float* b_joint  = (const float*)d_in[7];
  float* out = (float*)d_out;

  char* ws = (char*)d_ws;
  size_t off = 0;
  auto alloc = [&](size_t bytes) -> char* {
    char* p = ws + off;
    off += (bytes + 255) & ~(size_t)255;
    return p;
  };
  float* enc_p  = (float*)alloc((size_t)MTOT * JD * 4);    // 4 MB
  float* pred_p = (float*)alloc((size_t)UROWS * JD * 4);   // 1 MB
  size_t small_need = off;
  unsigned short* Wenc_p  = (unsigned short*)alloc((size_t)512 * 512 * 2);
  unsigned short* Wpred_p = (unsigned short*)alloc((size_t)640 * 512 * 2);
  unsigned short* Wjnt_p  = (unsigned short*)alloc((size_t)512 * 1024 * 2);
  size_t big_need = off;                                   // ~7.3 MB total

  if (ws_size >= big_need) {
    k_pack_all<<<544, 256, 0, stream>>>(W_enc, W_pred, W_joint,
                                        Wenc_p, Wpred_p, Wjnt_p);
    k_proj_both<<<320, 256, 0, stream>>>(enc_out, pred_out, Wenc_p, Wpred_p,
                                         b_enc, b_pred, enc_p, pred_p);
    k_fused<<<(ROWS / 128) * (VD / 256), 512, 0, stream>>>(enc_p, pred_p,
                                                           Wjnt_p, b_joint, out);
  } else if (ws_size >= small_need) {
    k_proj_naive<<<(MTOT * JD + 255) / 256, 256, 0, stream>>>(enc_out, W_enc, b_enc, enc_p, MTOT, 512, JD);
    k_proj_naive<<<(UROWS * JD + 255) / 256, 256, 0, stream>>>(pred_out, W_pred, b_pred, pred_p, UROWS, 640, JD);
    k_joint_naive<<<ROWS, 256, 0, stream>>>(enc_p, pred_p, W_joint, b_joint, out);
  }
  (void)in_sizes; (void)n_in; (void)out_size;
}